// Round 18
// baseline (282.644 us; speedup 1.0000x reference)
//
#include <hip/hip_runtime.h>
#include <cstdint>
#include <cstddef>

#define TN   8192
#define DD   512
#define NPER 4
#define KNN  5

typedef _Float16 f16x8 __attribute__((ext_vector_type(8)));
typedef float    f32x4 __attribute__((ext_vector_type(4)));
typedef unsigned int  u32;
typedef unsigned long long u64;

// key = sq_row - 2 * accHH / 4096^2  ->  fmaf(acc, -2^-23, sq_row)
#define KSCALE (-1.1920928955078125e-07f)

// ---------------------------------------------------------------------------
// u32 screen key: monotone f32 map, top 19 bits | 13-bit row idx. (R13-R17)
// ---------------------------------------------------------------------------
__device__ __forceinline__ u32 pk32(float key, int idx) {
  u32 kb = __float_as_uint(key);
  kb ^= (((int)kb >> 31) | 0x80000000u);
  return (kb & 0xFFFFE000u) | (u32)idx;
}

// branchless sorted-insert sweeps (v_min_u32/v_max_u32 pairs)
__device__ __forceinline__ void swins5(u32 v, u32 t[5]) {
#pragma unroll
  for (int s = 0; s < 5; ++s) {
    u32 lo = v < t[s] ? v : t[s];
    u32 hi = v < t[s] ? t[s] : v;
    t[s] = lo; v = hi;
  }
}
__device__ __forceinline__ void swins8(u32 v, u32 t[8]) {
#pragma unroll
  for (int s = 0; s < 8; ++s) {
    u32 lo = v < t[s] ? v : t[s];
    u32 hi = v < t[s] ? t[s] : v;
    t[s] = lo; v = hi;
  }
}

// u64 exact insert for the tiny refine kernel (proven R8-R17)
__device__ __forceinline__ u64 packkey64(float key, int idx) {
  u32 kb = __float_as_uint(key);
  kb ^= (((int)kb >> 31) | 0x80000000u);
  return ((u64)kb << 32) | (u32)idx;
}
__device__ __forceinline__ void ins8_64(u64 v, u64 tv[8]) {
  if (v < tv[7]) {
    tv[7] = v;
#pragma unroll
    for (int s = 7; s > 0; --s) {
      u64 lo = tv[s] < tv[s-1] ? tv[s] : tv[s-1];
      u64 hi = tv[s] < tv[s-1] ? tv[s-1] : tv[s];
      tv[s-1] = lo; tv[s] = hi;
    }
  }
}

// ---------------------------------------------------------------------------
// Kernel 0: H = f16(X*4096) in MFMA-fragment-blocked layout (R17-proven)
// FUSED with rowsq (saves one 16 MB X pass + a launch).
// Hb is [T/16 rowblks][16 kcs][1024 B]; byte lane*16 of a sub-panel holds
// lane's fragment: 8 f16 of row rowblk*16+lidx, k = kc*32 + lgrp*8..+7.
// Row r's squares: contributed by the 16 (wave,lgrp) lanes with lidx==r,
// each covering 32 elems -> LDS atomic-add then one writer per row.
// ---------------------------------------------------------------------------
__global__ void prep_blk(const float* __restrict__ X, _Float16* __restrict__ Hb,
                         float* __restrict__ rowsq) {
  __shared__ float rs[16];
  const int rb16 = (int)blockIdx.x;            // 0..511
  const int tid  = (int)threadIdx.x;
  const int lane = tid & 63;
  const int wv   = tid >> 6;
  const int lgrp = lane >> 4;
  const int lidx = lane & 15;
  if (tid < 16) rs[tid] = 0.f;
  __syncthreads();
  const float* src = X + (size_t)(rb16*16 + lidx) * DD + lgrp*8;
  float psum = 0.f;
#pragma unroll
  for (int i = 0; i < 4; ++i) {
    const int kc = wv*4 + i;
    const float4 x0 = *(const float4*)(src + kc*32);
    const float4 x1 = *(const float4*)(src + kc*32 + 4);
    float xs[8] = {x0.x, x0.y, x0.z, x0.w, x1.x, x1.y, x1.z, x1.w};
    f16x8 h;
#pragma unroll
    for (int j = 0; j < 8; ++j) {
      h[j] = (_Float16)(xs[j] * 4096.f);
      psum = fmaf(xs[j], xs[j], psum);
    }
    *(f16x8*)((char*)Hb + ((size_t)rb16*16 + kc)*1024 + lane*16) = h;
  }
  atomicAdd(&rs[lidx], psum);                  // LDS ds_add_f32
  __syncthreads();
  if (tid < 16) rowsq[rb16*16 + tid] = rs[tid];
}

// ---------------------------------------------------------------------------
// Kernel 1: HH screening GEMM + u32 screen-top selection.
// Blocked-layout loads (R17: contiguous 1 KB/instruction, -40%).
// NEW (R18): amdgpu_waves_per_eu(2,2) pins occupancy to EXACTLY 2 waves/EU
// -> 256-unified-reg budget, allocator can't aim at 128-and-spill (the
// R13/R14 failure). At 1 wave/SIMD (R17) MFMA+VALU serialize (one wave =
// one issue/cycle); 2 waves/SIMD lets them co-issue (m114). Pipeline
// reduced to 2-deep (R16: depth >2 is worthless; frag 96->64 regs, demand
// ~190-210 <= 256).
// C layout (m89): col = lane&15, row = 4*(lane>>4) + reg.
// partials: u32 [8192 centers][16 rsb][8].
// ---------------------------------------------------------------------------
__attribute__((amdgpu_flat_work_group_size(256, 256), amdgpu_waves_per_eu(2, 2)))
__global__ void gemm_top8(const _Float16* __restrict__ Hb,
                          const float* __restrict__ rowsq, u32* __restrict__ partials) {
  __shared__ u32 mg[128 * 8];                 // 4 KB wr-pair merge buffer
  const int tid  = (int)threadIdx.x;
  const int lane = tid & 63;
  const int w    = tid >> 6;                  // wave 0..3
  const int wr   = w >> 1, wc = w & 1;        // 2x2 wave grid
  // XCD swizzle (1024 % 8 == 0 -> bijective); cb fastest so consecutive
  // blocks on one XCD share the 512-row A panel (L2-resident).
  const int q    = ((int)blockIdx.x & 7) * 128 + ((int)blockIdx.x >> 3);
  const int cb   = q & 63;                    // 64 col-blocks of 128
  const int rsb  = q >> 6;                    // 16 row-superblocks of 512
  const int jb   = cb * 128;
  const int lgrp = lane >> 4;                 // k-group / C row-group
  const int lidx = lane & 15;                 // A-row / B-col within frag

  // blocked layout: sub-panel (rowblk, ks) at (rowblk*16 + ks)*1024 + lane*16
  const char* Bpb = (const char*)Hb + (size_t)(cb*8 + wc*4)*16384 + lane*16;

#define LOADF(dep, apb, ksv) do {                                               \
    _Pragma("unroll")                                                           \
    for (int t = 0; t < 4; ++t)                                                 \
      fa[dep][t] = *(const f16x8*)((apb) + t*16384 + (ksv)*1024);               \
    _Pragma("unroll")                                                           \
    for (int u = 0; u < 4; ++u)                                                 \
      fb[dep][u] = *(const f16x8*)(Bpb + u*16384 + (ksv)*1024);                 \
  } while (0)

#define MFMAS(dep) do {                                                         \
    _Pragma("unroll")                                                           \
    for (int rt = 0; rt < 4; ++rt)                                              \
      _Pragma("unroll")                                                         \
      for (int cf = 0; cf < 4; ++cf)                                            \
        acc[rt][cf] = __builtin_amdgcn_mfma_f32_16x16x32_f16(fa[dep][rt],       \
                                        fb[dep][cf], acc[rt][cf], 0, 0, 0);     \
  } while (0)

  u32 t5[4][5];                               // persistent per-cf screen lists
#pragma unroll
  for (int c = 0; c < 4; ++c)
#pragma unroll
    for (int s = 0; s < 5; ++s) t5[c][s] = 0xFFFFFFFFu;

  for (int tt = 0; tt < 4; ++tt) {            // 4 row-tiles of the superblock
    const int row0 = rsb * 512 + tt * 128;
    const char* Apb = (const char*)Hb + (size_t)(rsb*32 + tt*8 + wr*4)*16384 + lane*16;

    f32x4 acc[4][4] = {};
    f16x8 fa[2][4], fb[2][4];                 // 2-deep ping-pong
    LOADF(0, Apb, 0);
    LOADF(1, Apb, 1);
#pragma unroll
    for (int ks = 0; ks < 16; ++ks) {         // K = 512 in chunks of 32
      const int d = ks & 1;                   // static after full unroll
      MFMAS(d);
      if (ks + 2 < 16) LOADF(d, Apb, ks + 2); // issue 2 chunks ahead
    }

    float4 sqr[4];
#pragma unroll
    for (int t = 0; t < 4; ++t)
      sqr[t] = *(const float4*)(rowsq + row0 + wr*64 + t*16 + lgrp*4);

#pragma unroll
    for (int cf = 0; cf < 4; ++cf) {
      const int jc = jb + wc*64 + cf*16 + lidx;   // this lane's center column
#pragma unroll
      for (int t = 0; t < 4; ++t) {
        const int rbase = row0 + wr*64 + t*16 + lgrp*4;
        const float sx[4] = {sqr[t].x, sqr[t].y, sqr[t].z, sqr[t].w};
#pragma unroll
        for (int qq = 0; qq < 4; ++qq) {
          const int r = rbase + qq;
          const float key = fmaf(acc[t][cf][qq], KSCALE, sx[qq]);
          u32 v = pk32(key, r);
          v = (r == jc) ? 0xFFFFFFFFu : v;    // branchless self-exclusion
          swins5(v, t5[cf]);
        }
      }
    }
  }

  // ---- merges once per block ----
#pragma unroll
  for (int cf = 0; cf < 4; ++cf) {
    const int jc = jb + wc*64 + cf*16 + lidx;
    u32 t8[8];
#pragma unroll
    for (int s = 0; s < 5; ++s) t8[s] = t5[cf][s];
#pragma unroll
    for (int s = 5; s < 8; ++s) t8[s] = 0xFFFFFFFFu;
    {                                          // d=16: partner lgrp pair (snapshot t5)
      u32 ov[5];
#pragma unroll
      for (int s = 0; s < 5; ++s) ov[s] = __shfl_xor(t5[cf][s], 16, 64);
#pragma unroll
      for (int s = 0; s < 5; ++s) swins8(ov[s], t8);
    }
    {                                          // d=32 (snapshot t8)
      u32 ov[8];
#pragma unroll
      for (int s = 0; s < 8; ++s) ov[s] = __shfl_xor(t8[s], 32, 64);
#pragma unroll
      for (int s = 0; s < 8; ++s) swins8(ov[s], t8);
    }
    // wr-pair merge via LDS (the two wr waves cover different 256-row halves)
    if (wr == 1 && lane < 16) {
#pragma unroll
      for (int s = 0; s < 8; ++s) mg[(wc*64 + cf*16 + lidx)*8 + s] = t8[s];
    }
    __syncthreads();
    if (wr == 0 && lane < 16) {
      const u32* om = &mg[(wc*64 + cf*16 + lidx)*8];
#pragma unroll
      for (int s = 0; s < 8; ++s) swins8(om[s], t8);
      u32* pw = partials + ((size_t)jc * 16 + rsb) * 8;
#pragma unroll
      for (int s = 0; s < 8; ++s) pw[s] = t8[s];
    }
    __syncthreads();                          // mg reused next cf
  }
#undef LOADF
#undef MFMAS
}

// ---------------------------------------------------------------------------
// Kernel 2: fold 128 u32 screen entries per center -> cand[T][8].
// One wave per center, 2 entries per lane, snapshot butterfly. (R13-proven)
// ---------------------------------------------------------------------------
__global__ void merge_nn8(const u32* __restrict__ parts, u32* __restrict__ cand) {
  const int j    = (int)blockIdx.x * 4 + ((int)threadIdx.x >> 6);
  const int lane = (int)threadIdx.x & 63;
  u32 tv[8];
#pragma unroll
  for (int s = 0; s < 8; ++s) tv[s] = 0xFFFFFFFFu;
  swins8(parts[(size_t)j * 128 + lane], tv);
  swins8(parts[(size_t)j * 128 + 64 + lane], tv);
#pragma unroll
  for (int d = 1; d < 64; d <<= 1) {
    u32 ov[8];
#pragma unroll
    for (int s = 0; s < 8; ++s) ov[s] = __shfl_xor(tv[s], d, 64);
#pragma unroll
    for (int s = 0; s < 8; ++s) swins8(ov[s], tv);
  }
  if (lane == 0) {
#pragma unroll
    for (int s = 0; s < 8; ++s) cand[(size_t)j*8 + s] = tv[s];
  }
}

// ---------------------------------------------------------------------------
// Kernel 3: exact fp32 refine of the 8 candidates per center -> nn[T][5].
// (R8-proven; candidate idx = low 13 bits of the u32 screen entry)
// ---------------------------------------------------------------------------
__global__ void refine_nn(const float* __restrict__ X, const float* __restrict__ rowsq,
                          const u32* __restrict__ cand, int* __restrict__ nn) {
  const int j    = (int)blockIdx.x * 4 + ((int)threadIdx.x >> 6);   // center
  const int lane = (int)threadIdx.x & 63;
  const float4* xj = (const float4*)(X + (size_t)j * DD);
  const float4 qa = xj[lane];
  const float4 qb = xj[lane + 64];
  u64 best[8];
#pragma unroll
  for (int s = 0; s < 8; ++s) best[s] = ~0ull;
#pragma unroll
  for (int c = 0; c < 8; ++c) {
    const int r = (int)(cand[(size_t)j*8 + c] & 8191u);
    const float4* xr_ = (const float4*)(X + (size_t)r * DD);
    const float4 a = xr_[lane];
    const float4 b = xr_[lane + 64];
    float d = a.x*qa.x + a.y*qa.y + a.z*qa.z + a.w*qa.w
            + b.x*qb.x + b.y*qb.y + b.z*qb.z + b.w*qb.w;
#pragma unroll
    for (int off = 32; off >= 1; off >>= 1) d += __shfl_xor(d, off, 64);
    const float key = fmaf(-2.f, d, rowsq[r]);
    ins8_64(packkey64(key, r), best);         // every lane: identical result
  }
  if (lane == 0) {
#pragma unroll
    for (int s = 0; s < KNN; ++s) nn[j*KNN + s] = (int)(u32)best[s];
  }
}

// ---------------------------------------------------------------------------
// Kernel 4: synthesis  out[i*4+p] = x_i + g * (x_nn - x_i)  (verbatim, proven)
// ---------------------------------------------------------------------------
__global__ void synth_kernel(const float* __restrict__ X, const int* __restrict__ nn,
                             const float* __restrict__ gaps, const int* __restrict__ choice,
                             float* __restrict__ out) {
  const float4* X4 = (const float4*)X;
  float4* O4 = (float4*)out;
  const int base = (int)blockIdx.x * 256 + (int)threadIdx.x;
#pragma unroll
  for (int it = 0; it < 8; ++it) {
    const int f    = base + it * (2048 * 256);
    const int orow = f >> 7;
    const int d4   = f & 127;
    const int i    = orow >> 2;
    const int ch   = choice[orow];
    const int nr   = nn[i * KNN + ch];
    const float g  = gaps[orow];
    const float4 xi = X4[(size_t)i  * 128 + d4];
    const float4 xn = X4[(size_t)nr * 128 + d4];
    float4 r;
    r.x = fmaf(g, xn.x - xi.x, xi.x);
    r.y = fmaf(g, xn.y - xi.y, xi.y);
    r.z = fmaf(g, xn.z - xi.z, xi.z);
    r.w = fmaf(g, xn.w - xi.w, xi.w);
    O4[(size_t)orow * 128 + d4] = r;
  }
}

// ---------------------------------------------------------------------------
// d_out (64 MB) scratch: Hb[0,8M) | partials u32[8M,12M) | cand[12M,12.25M)
// — synth fully rewrites d_out last. d_ws: rowsq[32KB) + nn[160KB).
// ---------------------------------------------------------------------------
extern "C" void kernel_launch(void* const* d_in, const int* in_sizes, int n_in,
                              void* d_out, int out_size, void* d_ws, size_t ws_size,
                              hipStream_t stream) {
  const float* X      = (const float*)d_in[0];
  const float* gaps   = (const float*)d_in[1];
  const int*   choice = (const int*)  d_in[2];
  float* out = (float*)d_out;

  _Float16* Hb    = (_Float16*)d_out;                       // [0, 8M) blocked
  u32*      parts = (u32*)((char*)d_out + 8388608);         // [8M, 12M)
  u32*      cand  = (u32*)((char*)d_out + 12582912);        // [12M, 12.25M)

  float* rowsq = (float*)d_ws;                              // 32 KB
  int*   nn    = (int*)((char*)d_ws + TN * 4);              // 160 KB

  prep_blk    <<<512,  256, 0, stream>>>(X, Hb, rowsq);
  gemm_top8   <<<1024, 256, 0, stream>>>(Hb, rowsq, parts);
  merge_nn8   <<<2048, 256, 0, stream>>>(parts, cand);
  refine_nn   <<<2048, 256, 0, stream>>>(X, rowsq, cand, nn);
  synth_kernel<<<2048, 256, 0, stream>>>(X, nn, gaps, choice, out);
}

// Round 19
// 154.202 us; speedup vs baseline: 1.8329x; 1.8329x over previous
//
#include <hip/hip_runtime.h>
#include <cstdint>
#include <cstddef>

#define TN   8192
#define DD   512
#define NPER 4
#define KNN  5

typedef _Float16 f16x8 __attribute__((ext_vector_type(8)));
typedef float    f32x4 __attribute__((ext_vector_type(4)));
typedef unsigned int  u32;
typedef unsigned long long u64;

// key = sq_row - 2 * accHH / 4096^2  ->  fmaf(acc, -2^-23, sq_row)
#define KSCALE (-1.1920928955078125e-07f)

// ---------------------------------------------------------------------------
// u32 screen key: monotone f32 map, top 19 bits | 13-bit row idx.
// Keys are always positive (min inter-point d^2 ~ 600 >> fp16 error), so the
// negative-branch ashr is dead: xor sign bit + mask + or. (R13-R17 + trim)
// ---------------------------------------------------------------------------
__device__ __forceinline__ u32 pk32(float key, int idx) {
  u32 kb = __float_as_uint(key) ^ 0x80000000u;
  return (kb & 0xFFFFE000u) | (u32)idx;
}

// branchless sorted-insert sweeps (v_min_u32/v_max_u32 pairs)
__device__ __forceinline__ void swins5(u32 v, u32 t[5]) {
#pragma unroll
  for (int s = 0; s < 5; ++s) {
    u32 lo = v < t[s] ? v : t[s];
    u32 hi = v < t[s] ? t[s] : v;
    t[s] = lo; v = hi;
  }
}
__device__ __forceinline__ void swins8(u32 v, u32 t[8]) {
#pragma unroll
  for (int s = 0; s < 8; ++s) {
    u32 lo = v < t[s] ? v : t[s];
    u32 hi = v < t[s] ? t[s] : v;
    t[s] = lo; v = hi;
  }
}

// u64 exact insert for the tiny refine kernel (proven R8-R18)
__device__ __forceinline__ u64 packkey64(float key, int idx) {
  u32 kb = __float_as_uint(key);
  kb ^= (((int)kb >> 31) | 0x80000000u);
  return ((u64)kb << 32) | (u32)idx;
}
__device__ __forceinline__ void ins8_64(u64 v, u64 tv[8]) {
  if (v < tv[7]) {
    tv[7] = v;
#pragma unroll
    for (int s = 7; s > 0; --s) {
      u64 lo = tv[s] < tv[s-1] ? tv[s] : tv[s-1];
      u64 hi = tv[s] < tv[s-1] ? tv[s-1] : tv[s];
      tv[s-1] = lo; tv[s] = hi;
    }
  }
}

// ---------------------------------------------------------------------------
// Kernel 0: H = f16(X*4096) in MFMA-fragment-blocked layout, FUSED with
// rowsq (R18's prep, correctness-verified). Hb is [T/16][16 kcs][1024 B];
// byte lane*16 of a sub-panel = lane's fragment: 8 f16 of row rowblk*16+lidx,
// k = kc*32 + lgrp*8..+7  => every GEMM fragment load is one 1 KB burst.
// ---------------------------------------------------------------------------
__global__ void prep_blk(const float* __restrict__ X, _Float16* __restrict__ Hb,
                         float* __restrict__ rowsq) {
  __shared__ float rs[16];
  const int rb16 = (int)blockIdx.x;            // 0..511
  const int tid  = (int)threadIdx.x;
  const int lane = tid & 63;
  const int wv   = tid >> 6;
  const int lgrp = lane >> 4;
  const int lidx = lane & 15;
  if (tid < 16) rs[tid] = 0.f;
  __syncthreads();
  const float* src = X + (size_t)(rb16*16 + lidx) * DD + lgrp*8;
  float psum = 0.f;
#pragma unroll
  for (int i = 0; i < 4; ++i) {
    const int kc = wv*4 + i;
    const float4 x0 = *(const float4*)(src + kc*32);
    const float4 x1 = *(const float4*)(src + kc*32 + 4);
    float xs[8] = {x0.x, x0.y, x0.z, x0.w, x1.x, x1.y, x1.z, x1.w};
    f16x8 h;
#pragma unroll
    for (int j = 0; j < 8; ++j) {
      h[j] = (_Float16)(xs[j] * 4096.f);
      psum = fmaf(xs[j], xs[j], psum);
    }
    *(f16x8*)((char*)Hb + ((size_t)rb16*16 + kc)*1024 + lane*16) = h;
  }
  atomicAdd(&rs[lidx], psum);                  // LDS ds_add_f32
  __syncthreads();
  if (tid < 16) rowsq[rb16*16 + tid] = rs[tid];
}

// ---------------------------------------------------------------------------
// Kernel 1: HH screening GEMM + u32 screen-top selection — VERBATIM R17
// (the proven 125 us point). launch_bounds(256,1): 1 wave/SIMD, ZERO spill.
// R18 proved 2 waves/SIMD is register-infeasible for this working set
// (pinning to 2 waves forced a 128-reg budget -> 136 MB spill, 2x slower).
// At 1 wave/SIMD the kernel runs at the serial composition of its phases:
// loads ~60us (2 GB @ L2 BW) + MFMA ~27us + selection ~35us ~= 122us.
// Blocked layout (R17): every fragment load = contiguous 1 KB burst.
// 512-row superblock x 128 cols; per-(lane,cf) cap-5 lists persist across
// the 4 row-tiles; merges once per block. 3-deep fragment pipeline.
// C layout (m89): col = lane&15, row = 4*(lane>>4) + reg.
// partials: u32 [8192 centers][16 rsb][8].
// ---------------------------------------------------------------------------
__launch_bounds__(256, 1)
__global__ void gemm_top8(const _Float16* __restrict__ Hb,
                          const float* __restrict__ rowsq, u32* __restrict__ partials) {
  __shared__ u32 mg[128 * 8];                 // 4 KB wr-pair merge buffer
  const int tid  = (int)threadIdx.x;
  const int lane = tid & 63;
  const int w    = tid >> 6;                  // wave 0..3
  const int wr   = w >> 1, wc = w & 1;        // 2x2 wave grid
  // XCD swizzle (1024 % 8 == 0 -> bijective); cb fastest so consecutive
  // blocks on one XCD share the 512-row A panel (L2-resident).
  const int q    = ((int)blockIdx.x & 7) * 128 + ((int)blockIdx.x >> 3);
  const int cb   = q & 63;                    // 64 col-blocks of 128
  const int rsb  = q >> 6;                    // 16 row-superblocks of 512
  const int jb   = cb * 128;
  const int lgrp = lane >> 4;                 // k-group / C row-group
  const int lidx = lane & 15;                 // A-row / B-col within frag

  // blocked layout: sub-panel (rowblk, ks) at (rowblk*16 + ks)*1024 + lane*16
  const char* Bpb = (const char*)Hb + (size_t)(cb*8 + wc*4)*16384 + lane*16;

#define LOADF(dep, apb, ksv) do {                                               \
    _Pragma("unroll")                                                           \
    for (int t = 0; t < 4; ++t)                                                 \
      fa[dep][t] = *(const f16x8*)((apb) + t*16384 + (ksv)*1024);               \
    _Pragma("unroll")                                                           \
    for (int u = 0; u < 4; ++u)                                                 \
      fb[dep][u] = *(const f16x8*)(Bpb + u*16384 + (ksv)*1024);                 \
  } while (0)

#define MFMAS(dep) do {                                                         \
    _Pragma("unroll")                                                           \
    for (int rt = 0; rt < 4; ++rt)                                              \
      _Pragma("unroll")                                                         \
      for (int cf = 0; cf < 4; ++cf)                                            \
        acc[rt][cf] = __builtin_amdgcn_mfma_f32_16x16x32_f16(fa[dep][rt],       \
                                        fb[dep][cf], acc[rt][cf], 0, 0, 0);     \
  } while (0)

  u32 t5[4][5];                               // persistent per-cf screen lists
#pragma unroll
  for (int c = 0; c < 4; ++c)
#pragma unroll
    for (int s = 0; s < 5; ++s) t5[c][s] = 0xFFFFFFFFu;

  for (int tt = 0; tt < 4; ++tt) {            // 4 row-tiles of the superblock
    const int row0 = rsb * 512 + tt * 128;
    const char* Apb = (const char*)Hb + (size_t)(rsb*32 + tt*8 + wr*4)*16384 + lane*16;

    f32x4 acc[4][4] = {};
    f16x8 fa[3][4], fb[3][4];                 // 3-deep pipeline buffers
    LOADF(0, Apb, 0);
    LOADF(1, Apb, 1);
    LOADF(2, Apb, 2);
#pragma unroll
    for (int ks = 0; ks < 16; ++ks) {         // K = 512 in chunks of 32
      const int d = ks % 3;                   // static after full unroll
      MFMAS(d);
      if (ks + 3 < 16) LOADF(d, Apb, ks + 3); // issue 3 chunks ahead
    }

    float4 sqr[4];
#pragma unroll
    for (int t = 0; t < 4; ++t)
      sqr[t] = *(const float4*)(rowsq + row0 + wr*64 + t*16 + lgrp*4);

#pragma unroll
    for (int cf = 0; cf < 4; ++cf) {
      const int jc = jb + wc*64 + cf*16 + lidx;   // this lane's center column
#pragma unroll
      for (int t = 0; t < 4; ++t) {
        const int rbase = row0 + wr*64 + t*16 + lgrp*4;
        const float sx[4] = {sqr[t].x, sqr[t].y, sqr[t].z, sqr[t].w};
#pragma unroll
        for (int qq = 0; qq < 4; ++qq) {
          const int r = rbase + qq;
          const float key = fmaf(acc[t][cf][qq], KSCALE, sx[qq]);
          u32 v = pk32(key, r);
          v = (r == jc) ? 0xFFFFFFFFu : v;    // branchless self-exclusion
          swins5(v, t5[cf]);
        }
      }
    }
  }

  // ---- merges once per block ----
#pragma unroll
  for (int cf = 0; cf < 4; ++cf) {
    const int jc = jb + wc*64 + cf*16 + lidx;
    u32 t8[8];
#pragma unroll
    for (int s = 0; s < 5; ++s) t8[s] = t5[cf][s];
#pragma unroll
    for (int s = 5; s < 8; ++s) t8[s] = 0xFFFFFFFFu;
    {                                          // d=16: partner lgrp pair (snapshot t5)
      u32 ov[5];
#pragma unroll
      for (int s = 0; s < 5; ++s) ov[s] = __shfl_xor(t5[cf][s], 16, 64);
#pragma unroll
      for (int s = 0; s < 5; ++s) swins8(ov[s], t8);
    }
    {                                          // d=32 (snapshot t8)
      u32 ov[8];
#pragma unroll
      for (int s = 0; s < 8; ++s) ov[s] = __shfl_xor(t8[s], 32, 64);
#pragma unroll
      for (int s = 0; s < 8; ++s) swins8(ov[s], t8);
    }
    // wr-pair merge via LDS (the two wr waves cover different 256-row halves)
    if (wr == 1 && lane < 16) {
#pragma unroll
      for (int s = 0; s < 8; ++s) mg[(wc*64 + cf*16 + lidx)*8 + s] = t8[s];
    }
    __syncthreads();
    if (wr == 0 && lane < 16) {
      const u32* om = &mg[(wc*64 + cf*16 + lidx)*8];
#pragma unroll
      for (int s = 0; s < 8; ++s) swins8(om[s], t8);
      u32* pw = partials + ((size_t)jc * 16 + rsb) * 8;
#pragma unroll
      for (int s = 0; s < 8; ++s) pw[s] = t8[s];
    }
    __syncthreads();                          // mg reused next cf
  }
#undef LOADF
#undef MFMAS
}

// ---------------------------------------------------------------------------
// Kernel 2: fold 128 u32 screen entries per center -> cand[T][8].
// One wave per center, 2 entries per lane, snapshot butterfly. (R13-proven)
// ---------------------------------------------------------------------------
__global__ void merge_nn8(const u32* __restrict__ parts, u32* __restrict__ cand) {
  const int j    = (int)blockIdx.x * 4 + ((int)threadIdx.x >> 6);
  const int lane = (int)threadIdx.x & 63;
  u32 tv[8];
#pragma unroll
  for (int s = 0; s < 8; ++s) tv[s] = 0xFFFFFFFFu;
  swins8(parts[(size_t)j * 128 + lane], tv);
  swins8(parts[(size_t)j * 128 + 64 + lane], tv);
#pragma unroll
  for (int d = 1; d < 64; d <<= 1) {
    u32 ov[8];
#pragma unroll
    for (int s = 0; s < 8; ++s) ov[s] = __shfl_xor(tv[s], d, 64);
#pragma unroll
    for (int s = 0; s < 8; ++s) swins8(ov[s], tv);
  }
  if (lane == 0) {
#pragma unroll
    for (int s = 0; s < 8; ++s) cand[(size_t)j*8 + s] = tv[s];
  }
}

// ---------------------------------------------------------------------------
// Kernel 3: exact fp32 refine of the 8 candidates per center -> nn[T][5].
// (R8-proven; candidate idx = low 13 bits of the u32 screen entry)
// ---------------------------------------------------------------------------
__global__ void refine_nn(const float* __restrict__ X, const float* __restrict__ rowsq,
                          const u32* __restrict__ cand, int* __restrict__ nn) {
  const int j    = (int)blockIdx.x * 4 + ((int)threadIdx.x >> 6);   // center
  const int lane = (int)threadIdx.x & 63;
  const float4* xj = (const float4*)(X + (size_t)j * DD);
  const float4 qa = xj[lane];
  const float4 qb = xj[lane + 64];
  u64 best[8];
#pragma unroll
  for (int s = 0; s < 8; ++s) best[s] = ~0ull;
#pragma unroll
  for (int c = 0; c < 8; ++c) {
    const int r = (int)(cand[(size_t)j*8 + c] & 8191u);
    const float4* xr_ = (const float4*)(X + (size_t)r * DD);
    const float4 a = xr_[lane];
    const float4 b = xr_[lane + 64];
    float d = a.x*qa.x + a.y*qa.y + a.z*qa.z + a.w*qa.w
            + b.x*qb.x + b.y*qb.y + b.z*qb.z + b.w*qb.w;
#pragma unroll
    for (int off = 32; off >= 1; off >>= 1) d += __shfl_xor(d, off, 64);
    const float key = fmaf(-2.f, d, rowsq[r]);
    ins8_64(packkey64(key, r), best);         // every lane: identical result
  }
  if (lane == 0) {
#pragma unroll
    for (int s = 0; s < KNN; ++s) nn[j*KNN + s] = (int)(u32)best[s];
  }
}

// ---------------------------------------------------------------------------
// Kernel 4: synthesis  out[i*4+p] = x_i + g * (x_nn - x_i)  (verbatim, proven)
// ---------------------------------------------------------------------------
__global__ void synth_kernel(const float* __restrict__ X, const int* __restrict__ nn,
                             const float* __restrict__ gaps, const int* __restrict__ choice,
                             float* __restrict__ out) {
  const float4* X4 = (const float4*)X;
  float4* O4 = (float4*)out;
  const int base = (int)blockIdx.x * 256 + (int)threadIdx.x;
#pragma unroll
  for (int it = 0; it < 8; ++it) {
    const int f    = base + it * (2048 * 256);
    const int orow = f >> 7;
    const int d4   = f & 127;
    const int i    = orow >> 2;
    const int ch   = choice[orow];
    const int nr   = nn[i * KNN + ch];
    const float g  = gaps[orow];
    const float4 xi = X4[(size_t)i  * 128 + d4];
    const float4 xn = X4[(size_t)nr * 128 + d4];
    float4 r;
    r.x = fmaf(g, xn.x - xi.x, xi.x);
    r.y = fmaf(g, xn.y - xi.y, xi.y);
    r.z = fmaf(g, xn.z - xi.z, xi.z);
    r.w = fmaf(g, xn.w - xi.w, xi.w);
    O4[(size_t)orow * 128 + d4] = r;
  }
}

// ---------------------------------------------------------------------------
// d_out (64 MB) scratch: Hb[0,8M) | partials u32[8M,12M) | cand[12M,12.25M)
// — synth fully rewrites d_out last. d_ws: rowsq[32KB) + nn[160KB).
// ---------------------------------------------------------------------------
extern "C" void kernel_launch(void* const* d_in, const int* in_sizes, int n_in,
                              void* d_out, int out_size, void* d_ws, size_t ws_size,
                              hipStream_t stream) {
  const float* X      = (const float*)d_in[0];
  const float* gaps   = (const float*)d_in[1];
  const int*   choice = (const int*)  d_in[2];
  float* out = (float*)d_out;

  _Float16* Hb    = (_Float16*)d_out;                       // [0, 8M) blocked
  u32*      parts = (u32*)((char*)d_out + 8388608);         // [8M, 12M)
  u32*      cand  = (u32*)((char*)d_out + 12582912);        // [12M, 12.25M)

  float* rowsq = (float*)d_ws;                              // 32 KB
  int*   nn    = (int*)((char*)d_ws + TN * 4);              // 160 KB

  prep_blk    <<<512,  256, 0, stream>>>(X, Hb, rowsq);
  gemm_top8   <<<1024, 256, 0, stream>>>(Hb, rowsq, parts);
  merge_nn8   <<<2048, 256, 0, stream>>>(parts, cand);
  refine_nn   <<<2048, 256, 0, stream>>>(X, rowsq, cand, nn);
  synth_kernel<<<2048, 256, 0, stream>>>(X, nn, gaps, choice, out);
}